// Round 4
// baseline (567.380 us; speedup 1.0000x reference)
//
#include <hip/hip_runtime.h>
#include <hip/hip_fp16.h>
#include <cstdint>
#include <cmath>

#define TOKENS  16384
#define HIDDEN  4096
#define NEXP    256
#define TOPK    8
#define KDROP   4   /* n_group - topk_group */

typedef _Float16 f16x8  __attribute__((ext_vector_type(8)));
typedef float    f32x16 __attribute__((ext_vector_type(16)));

#define LO_SCALE 2048.0f          /* 2^11 */
#define LO_INV   (1.0f/2048.0f)

// ws layout (bytes):
//   [0, 16777216)            gates0 fp32 [TOKENS][NEXP]   (K-half 0)
//   [16777216, +16777216)    gates1 fp32 [TOKENS][NEXP]   (K-half 1)
//   [33554432, +2097152)     w_h  f16 chunk-array
//   [35651584, +2097152)     w_l  f16 chunk-array (scaled by 2^11)
#define WS_G0_OFF 0
#define WS_G1_OFF 16777216
#define WS_WH_OFF 33554432
#define WS_WL_OFF 35651584

// ---------------------------------------------------------------------------
// Pre-kernel: split w (fp32) into f16 hi / (lo*2^11) stored in MFMA-frag
// chunk order: chunk (e,k8grp) -> cid = ((kc*2+s)*8 + e/32)*64 + hl*32 + e%32
// where kc=k/32, s=(k/16)%2, hl=(k/8)%2.  Each chunk = 8 consecutive k f16.
// ---------------------------------------------------------------------------
__global__ __launch_bounds__(256)
void wsplit(const float* __restrict__ w, _Float16* __restrict__ wh,
            _Float16* __restrict__ wl)
{
    const int idx = blockIdx.x * 256 + threadIdx.x;   // 0..131071
    const int e   = idx >> 9;                         // expert 0..255
    const int kg8 = idx & 511;                        // 8-k group
    const float4* p = (const float4*)(w + (size_t)e * HIDDEN + kg8 * 8);
    float4 f0 = p[0], f1 = p[1];
    float v[8] = {f0.x, f0.y, f0.z, f0.w, f1.x, f1.y, f1.z, f1.w};
    f16x8 hi, lo;
    #pragma unroll
    for (int i = 0; i < 8; ++i) {
        _Float16 h = (_Float16)v[i];
        hi[i] = h;
        lo[i] = (_Float16)((v[i] - (float)h) * LO_SCALE);
    }
    const int kc = kg8 >> 2, s = (kg8 >> 1) & 1, hl = kg8 & 1;
    const int cid = ((kc * 2 + s) * 8 + (e >> 5)) * 64 + hl * 32 + (e & 31);
    ((f16x8*)wh)[cid] = hi;
    ((f16x8*)wl)[cid] = lo;
}

// ---------------------------------------------------------------------------
// GEMM: gates_half = x @ W^T (one K-half per blockIdx.y) via split-f16 MFMA.
// Block: 128 tokens x 256 experts, grid (128,2) = 256 blocks = 1 per CU.
// __launch_bounds__(256,1): 512-VGPR budget -> no spills, loads hoist.
// Wave wv: experts [wv*64, wv*64+64), all 128 tokens: 4x2 MFMA tiles of 32x32,
// 3 products each (hi*hi; lo*hi + hi*lo scaled by 2^11).
// A: LDS double-buffer, register prefetch distance 2 (covers HBM latency).
// B: register prefetch distance 1 straight from chunk-ordered L2-resident wh/wl.
// One barrier per iteration. Plain stores (no atomics).
// ---------------------------------------------------------------------------
__global__ __launch_bounds__(256, 1)
void gemm_split(const float* __restrict__ x, const _Float16* __restrict__ wh,
                const _Float16* __restrict__ wl,
                float* __restrict__ g0, float* __restrict__ g1)
{
    __shared__ _Float16 Ah[2][128 * 32];   // 2 x 8 KB, chunk-array order
    __shared__ _Float16 Al[2][128 * 32];   // 2 x 8 KB

    const int tid  = threadIdx.x;
    const int wv   = tid >> 6;
    const int lane = tid & 63;
    const int tok0 = blockIdx.x * 128;
    const int kcg0 = blockIdx.y * 64;   // first 32-k chunk of this K-half
    float* gates_half = blockIdx.y ? g1 : g0;

    // A staging: thread t handles row r = t>>1, k-groups {2p, 2p+1}, p = t&1.
    // chunk id for (row r, kgroup g): (s*4 + r/32)*64 + hl*32 + r%32,
    // with s = g>>1, hl = g&1.
    const int sr = tid >> 1;            // local token row 0..127
    const int sp = tid & 1;             // k-group pair 0..1
    const float* xr = x + (size_t)(tok0 + sr) * HIDDEN + sp * 16;
    const int mt_s   = sr >> 5;
    const int m_s    = sr & 31;
    // chunk ids for the two groups this thread stages (g = 2sp, 2sp+1):
    const int scid0 = ((sp * 4) + mt_s) * 64 + 0 * 32 + m_s + (sp ? 0 : 0);
    // g=2sp   -> s=sp, hl=0 : cid = (sp*4+mt)*64 + m
    // g=2sp+1 -> s=sp, hl=1 : cid = (sp*4+mt)*64 + 32 + m
    const int scidA = (sp * 4 + mt_s) * 64 + m_s;        // hl = 0
    const int scidB = scidA + 32;                        // hl = 1

    const f16x8* whc = (const f16x8*)wh;
    const f16x8* wlc = (const f16x8*)wl;

    f32x16 accH[4][2] = {};   // hi*hi
    f32x16 accX[4][2] = {};   // (lo*hi + hi*lo), scaled by 2^11

    f16x8 bh[2][2], bl[2][2];   // current iteration's B frags [kstep s][ntile c]
    float4 ar[4];               // raw A prefetch (regs1): next tile's 2x32B

    // ---- prologue: A(0) -> LDS[0] direct, A(1) -> regs, B(0) -> regs
    {
        const float4* ap0 = (const float4*)(xr + (size_t)kcg0 * 32);
        float4 f0 = ap0[0], f1 = ap0[1];
        const float4* ap1 = (const float4*)(xr + (size_t)(kcg0 + 1) * 32);
        ar[0] = ap1[0]; ar[1] = ap1[1];
        ar[2] = ap1[0]; ar[3] = ap1[1];   // placeholder, overwritten below
        // (ar[2..3] unused in prologue path; real layout: ar[0..3] = 4 float4
        //  covering both 8-k groups of the next chunk)
        ar[0] = ap1[0]; ar[1] = ap1[1];

        #pragma unroll
        for (int s = 0; s < 2; ++s) {
            const int base = (((size_t)0 + kcg0) * 2 + s) * 8 * 64 + wv * 2 * 64 + lane;
            bh[s][0] = whc[base];
            bh[s][1] = whc[base + 64];
            bl[s][0] = wlc[base];
            bl[s][1] = wlc[base + 64];
        }
        float v[8] = {f0.x, f0.y, f0.z, f0.w, f1.x, f1.y, f1.z, f1.w};
        f16x8 hi, lo;
        #pragma unroll
        for (int i = 0; i < 8; ++i) {
            _Float16 h = (_Float16)v[i];
            hi[i] = h;
            lo[i] = (_Float16)((v[i] - (float)h) * LO_SCALE);
        }
        // thread stages 16 consecutive floats = groups g=2sp (hl0), 2sp+1 (hl1)
        *(f16x8*)&Ah[0][scidA * 8] = *(f16x8*)&hi;   // first 8 -> hl=0
        // split hi/lo into the two 8-k chunks:
        f16x8 hiA, loA, hiB, loB;
        #pragma unroll
        for (int i = 0; i < 8; ++i) { hiA[i] = hi[i]; loA[i] = lo[i]; }
        *(f16x8*)&Ah[0][scidA * 8] = hiA;
        *(f16x8*)&Al[0][scidA * 8] = loA;
        // second 8 floats of this thread's 16-float slice:
        float v2[8] = {0,0,0,0,0,0,0,0};
        const float4* ap0b = ap0 + 2;
        float4 f2 = ap0b[0], f3 = ap0b[1];
        float vb[8] = {f2.x, f2.y, f2.z, f2.w, f3.x, f3.y, f3.z, f3.w};
        #pragma unroll
        for (int i = 0; i < 8; ++i) {
            _Float16 h = (_Float16)vb[i];
            hiB[i] = h;
            loB[i] = (_Float16)((vb[i] - (float)h) * LO_SCALE);
        }
        *(f16x8*)&Ah[0][scidB * 8] = hiB;
        *(f16x8*)&Al[0][scidB * 8] = loB;
        (void)v2;
        // A(1) full prefetch: 4 float4 = 16 floats
        ar[0] = ap1[0]; ar[1] = ap1[1]; ar[2] = ap1[2]; ar[3] = ap1[3];
    }
    __syncthreads();

    #pragma unroll 2
    for (int kc = 0; kc < 64; ++kc) {
        const int cur = kc & 1;

        // ---- prefetch A(kc+2) raw and B(kc+1) frags into registers
        float4 arn[4];
        f16x8 bhn[2][2], bln[2][2];
        if (kc < 62) {
            const float4* ap = (const float4*)(xr + (size_t)(kcg0 + kc + 2) * 32);
            arn[0] = ap[0]; arn[1] = ap[1]; arn[2] = ap[2]; arn[3] = ap[3];
        }
        if (kc < 63) {
            const int kcg = kcg0 + kc + 1;
            #pragma unroll
            for (int s = 0; s < 2; ++s) {
                const int base = ((kcg * 2 + s) * 8 + wv * 2) * 64 + lane;
                bhn[s][0] = whc[base];
                bhn[s][1] = whc[base + 64];
                bln[s][0] = wlc[base];
                bln[s][1] = wlc[base + 64];
            }
        }

        // ---- compute on LDS[cur] with current B regs
        #pragma unroll
        for (int s = 0; s < 2; ++s) {
            f16x8 ah[4], al[4];
            #pragma unroll
            for (int mt = 0; mt < 4; ++mt) {
                ah[mt] = *(const f16x8*)&Ah[cur][((s * 4 + mt) * 64 + lane) * 8];
                al[mt] = *(const f16x8*)&Al[cur][((s * 4 + mt) * 64 + lane) * 8];
            }
            #pragma unroll
            for (int mt = 0; mt < 4; ++mt) {
                #pragma unroll
                for (int c = 0; c < 2; ++c) {
                    accH[mt][c] = __builtin_amdgcn_mfma_f32_32x32x16_f16(ah[mt], bh[s][c], accH[mt][c], 0, 0, 0);
                    accX[mt][c] = __builtin_amdgcn_mfma_f32_32x32x16_f16(al[mt], bh[s][c], accX[mt][c], 0, 0, 0);
                    accX[mt][c] = __builtin_amdgcn_mfma_f32_32x32x16_f16(ah[mt], bl[s][c], accX[mt][c], 0, 0, 0);
                }
            }
        }

        // ---- store A(kc+1) (held in ar) into the other LDS buffer; rotate
        if (kc < 63) {
            float va[8] = {ar[0].x, ar[0].y, ar[0].z, ar[0].w,
                           ar[1].x, ar[1].y, ar[1].z, ar[1].w};
            float vb[8] = {ar[2].x, ar[2].y, ar[2].z, ar[2].w,
                           ar[3].x, ar[3].y, ar[3].z, ar[3].w};
            f16x8 hiA, loA, hiB, loB;
            #pragma unroll
            for (int i = 0; i < 8; ++i) {
                _Float16 hA = (_Float16)va[i];
                hiA[i] = hA;
                loA[i] = (_Float16)((va[i] - (float)hA) * LO_SCALE);
                _Float16 hB = (_Float16)vb[i];
                hiB[i] = hB;
                loB[i] = (_Float16)((vb[i] - (float)hB) * LO_SCALE);
            }
            *(f16x8*)&Ah[cur ^ 1][scidA * 8] = hiA;
            *(f16x8*)&Al[cur ^ 1][scidA * 8] = loA;
            *(f16x8*)&Ah[cur ^ 1][scidB * 8] = hiB;
            *(f16x8*)&Al[cur ^ 1][scidB * 8] = loB;
            #pragma unroll
            for (int i = 0; i < 4; ++i) ar[i] = arn[i];
            #pragma unroll
            for (int s = 0; s < 2; ++s) {
                bh[s][0] = bhn[s][0]; bh[s][1] = bhn[s][1];
                bl[s][0] = bln[s][0]; bl[s][1] = bln[s][1];
            }
        }
        __syncthreads();
    }

    // ---- epilogue: combine hi + lo*2^-11, plain stores (no atomics)
    const int col   = lane & 31;
    const int rbase = 4 * (lane >> 5);
    #pragma unroll
    for (int mt = 0; mt < 4; ++mt)
        #pragma unroll
        for (int c = 0; c < 2; ++c) {
            float* gp = gates_half + (size_t)(tok0 + mt * 32) * NEXP + wv * 64 + c * 32 + col;
            #pragma unroll
            for (int reg = 0; reg < 16; ++reg) {
                const int row = (reg & 3) + 8 * (reg >> 2) + rbase;
                gp[(size_t)row * NEXP] = accH[mt][c][reg] + accX[mt][c][reg] * LO_INV;
            }
        }
}

// ---------------------------------------------------------------------------
// Gating epilogue: one wave per token; sums the two K-half gate buffers.
// All-register top-k (no dynamic array indexing -> no scratch).
// ---------------------------------------------------------------------------
__device__ __forceinline__ unsigned ordkey(float f) {
    unsigned u = __float_as_uint(f);
    return (u & 0x80000000u) ? ~u : (u | 0x80000000u);  // monotone float->uint
}

__global__ __launch_bounds__(256, 4)
void gate_epilogue(const float* __restrict__ g0,
                   const float* __restrict__ g1,
                   const float* __restrict__ bias,
                   float* __restrict__ out)
{
    const int tid  = threadIdx.x;
    const int wv   = tid >> 6;
    const int lane = tid & 63;
    const int t    = blockIdx.x * 4 + wv;

    float4 ga = ((const float4*)(g0 + (size_t)t * NEXP))[lane];
    float4 gb = ((const float4*)(g1 + (size_t)t * NEXP))[lane];
    float4 bv = ((const float4*)bias)[lane];
    float4 gv = make_float4(ga.x + gb.x, ga.y + gb.y, ga.z + gb.z, ga.w + gb.w);

    float sig0 = 1.0f / (1.0f + expf(-gv.x));
    float sig1 = 1.0f / (1.0f + expf(-gv.y));
    float sig2 = 1.0f / (1.0f + expf(-gv.z));
    float sig3 = 1.0f / (1.0f + expf(-gv.w));
    float sc0 = sig0 + bv.x, sc1 = sig1 + bv.y;
    float sc2 = sig2 + bv.z, sc3 = sig3 + bv.w;

    // top-2 of my 4 scores
    float m1 = fmaxf(sc0, sc1);
    float m2 = fminf(sc0, sc1);
    if (sc2 > m1) { m2 = m1; m1 = sc2; } else m2 = fmaxf(m2, sc2);
    if (sc3 > m1) { m2 = m1; m1 = sc3; } else m2 = fmaxf(m2, sc3);
    // merge across the 8 lanes of this group (group = lane>>3, 32 experts)
    #pragma unroll
    for (int off = 1; off < 8; off <<= 1) {
        float o1 = __shfl_xor(m1, off);
        float o2 = __shfl_xor(m2, off);
        float nm1 = fmaxf(m1, o1);
        float nm2 = fmaxf(fminf(m1, o1), fmaxf(m2, o2));
        m1 = nm1; m2 = nm2;
    }
    float gsum = m1 + m2;
    float gs[8];
    #pragma unroll
    for (int gi = 0; gi < 8; ++gi) gs[gi] = __shfl(gsum, gi * 8);

    // keep the KDROP smallest groups (tie -> lower index), faithful to ref
    int keepmask = 0;
    #pragma unroll
    for (int g = 0; g < 8; ++g) {
        int rank = 0;
        #pragma unroll
        for (int h = 0; h < 8; ++h)
            rank += (gs[h] < gs[g]) || (gs[h] == gs[g] && h < g);
        if (rank < KDROP) keepmask |= (1 << g);
    }
    const bool kept = (keepmask >> (lane >> 3)) & 1;

    // lexicographic (value asc, index asc) keys; masked entries = +0.0
    const unsigned ib = (unsigned)(lane * 4);
    unsigned long long k0 = ((unsigned long long)ordkey(kept ? sc0 : 0.0f) << 32) | (ib + 0);
    unsigned long long k1 = ((unsigned long long)ordkey(kept ? sc1 : 0.0f) << 32) | (ib + 1);
    unsigned long long k2 = ((unsigned long long)ordkey(kept ? sc2 : 0.0f) << 32) | (ib + 2);
    unsigned long long k3 = ((unsigned long long)ordkey(kept ? sc3 : 0.0f) << 32) | (ib + 3);

    float ssum = 0.0f, myval = 0.0f;
    int myidx = 0;
    #pragma unroll
    for (int r = 0; r < TOPK; ++r) {
        unsigned long long kmin = k0 < k1 ? k0 : k1;
        if (k2 < kmin) kmin = k2;
        if (k3 < kmin) kmin = k3;
        #pragma unroll
        for (int off = 32; off >= 1; off >>= 1) {
            unsigned long long o = __shfl_xor(kmin, off);
            if (o < kmin) kmin = o;
        }
        const int id   = (int)(kmin & 0xffffffffull);
        const int src  = id >> 2;   // owning lane (wave-uniform)
        const int slot = id & 3;    // wave-uniform
        float vsrc = (slot == 0) ? sig0 : (slot == 1) ? sig1
                   : (slot == 2) ? sig2 : sig3;
        float v = __shfl(vsrc, src);
        ssum += v;
        if (lane == r) { myidx = id; myval = v; }
        const bool mine = (lane == src);
        if (mine && slot == 0) k0 = ~0ull;
        if (mine && slot == 1) k1 = ~0ull;
        if (mine && slot == 2) k2 = ~0ull;
        if (mine && slot == 3) k3 = ~0ull;
    }

    if (lane < TOPK) {
        out[(size_t)t * TOPK + lane] = (float)myidx;                      // inds
        out[(size_t)TOKENS * TOPK + (size_t)t * TOPK + lane] =
            myval / (ssum + 1e-20f) * 2.5f;                               // sel
    }
}

// ---------------------------------------------------------------------------
extern "C" void kernel_launch(void* const* d_in, const int* in_sizes, int n_in,
                              void* d_out, int out_size, void* d_ws, size_t ws_size,
                              hipStream_t stream)
{
    const float* x    = (const float*)d_in[0];
    const float* w    = (const float*)d_in[1];
    const float* bias = (const float*)d_in[2];
    float* out = (float*)d_out;

    float*     g0 = (float*)((char*)d_ws + WS_G0_OFF);
    float*     g1 = (float*)((char*)d_ws + WS_G1_OFF);
    _Float16*  wh = (_Float16*)((char*)d_ws + WS_WH_OFF);
    _Float16*  wl = (_Float16*)((char*)d_ws + WS_WL_OFF);

    // split w into chunk-ordered f16 hi/lo
    wsplit<<<dim3(512), dim3(256), 0, stream>>>(w, wh, wl);
    // split-f16 MFMA GEMM: 128-token blocks, K-split 2, 256 blocks (1/CU)
    gemm_split<<<dim3(TOKENS / 128, 2), dim3(256), 0, stream>>>(x, wh, wl, g0, g1);
    // gating epilogue sums the halves
    gate_epilogue<<<dim3(TOKENS / 4), dim3(256), 0, stream>>>(g0, g1, bias, out);
}